// Round 5
// baseline (2089.449 us; speedup 1.0000x reference)
//
#include <hip/hip_runtime.h>
#include <stdint.h>

// LSTM (B=128, T=512, I=64, H=512) persistent kernel, round 5:
//  - 32 groups x 4 batches; 8 blocks/group, 64 units/block, W in VGPRs (2 tiles)
//  - protocol v5: tagged data granules + per-wave sentinels; ONLY wave0 polls
//    (64 sentinels = 512B/iter, 16x less MALL poll traffic), LDS 'go' broadcast,
//    per-granule tag verify as fallback (correct even if vmcnt!=visibility)
//  - 4 independent MFMA accumulator chains (halved dependent-MFMA wall)
//  - DPP-paired full-dword LDS scatter (0 bank conflicts), masked b128 reads

#define T_STEPS 512
#define HID 512
#define IND 64
#define NGROUPS 32
#define BPG 8           // blocks per group
#define BATCH_PG 4      // batches per group
#define UPB 64          // hidden units per block
#define NTHREADS 512    // 8 waves; wave w owns gate-cols [w*32, w*32+32) (2 tiles)

typedef float f32x4 __attribute__((ext_vector_type(4)));
typedef short s16x8 __attribute__((ext_vector_type(8)));
typedef unsigned long long u64_t;

#define ALOAD64(p)    __hip_atomic_load((p), __ATOMIC_RELAXED, __HIP_MEMORY_SCOPE_AGENT)
#define ASTORE64(p,v) __hip_atomic_store((p), (v), __ATOMIC_RELAXED, __HIP_MEMORY_SCOPE_AGENT)

__device__ inline unsigned short f2bf(float f) {
  uint32_t u = __builtin_bit_cast(uint32_t, f);
  u += 0x7fffu + ((u >> 16) & 1u);   // RNE (finite inputs)
  return (unsigned short)(u >> 16);
}

__device__ inline s16x8 pack8(f32x4 a, f32x4 b) {
  s16x8 r;
  r[0] = (short)f2bf(a[0]); r[1] = (short)f2bf(a[1]);
  r[2] = (short)f2bf(a[2]); r[3] = (short)f2bf(a[3]);
  r[4] = (short)f2bf(b[0]); r[5] = (short)f2bf(b[1]);
  r[6] = (short)f2bf(b[2]); r[7] = (short)f2bf(b[3]);
  return r;
}

template <int CTRL>
__device__ inline float qbc(float v) {   // quad_perm broadcast via DPP (VALU)
  int i = __builtin_bit_cast(int, v);
  return __builtin_bit_cast(float,
      __builtin_amdgcn_update_dpp(i, i, CTRL, 0xF, 0xF, false));
}

__device__ inline unsigned qswap(unsigned v) {  // quad_perm [1,0,3,2]
  int i = __builtin_bit_cast(int, v);
  return (unsigned)__builtin_amdgcn_update_dpp(i, i, 0xB1, 0xF, 0xF, false);
}

__global__ void __launch_bounds__(NTHREADS, 2)
lstm_persist(const float* __restrict__ x,   const float* __restrict__ Wih,
             const float* __restrict__ Whh, const float* __restrict__ bih,
             const float* __restrict__ bhh, const float* __restrict__ Wcls,
             const float* __restrict__ bcls, float* __restrict__ out,
             u64_t* __restrict__ hx,    // [2][NGROUPS][1024] tagged granules, memset 0
             u64_t* __restrict__ sent)  // [2][NGROUPS][64] wave sentinels, memset 0
{
  __shared__ unsigned short hsm[2][4 * HID];      // 2 x 4KB A-tile (rows 0..3)
  __shared__ float clsh[BATCH_PG][UPB];           // 1KB final-h for classifier
  __shared__ int go_flag;

  const int g    = blockIdx.x / BPG;
  const int blk  = blockIdx.x % BPG;
  const int tid  = threadIdx.x;
  const int w    = tid >> 6;
  const int lane = tid & 63;
  const int lrow = lane & 15;   // A row / D col
  const int lk   = lane >> 4;   // K subgroup

  // ---- persistent weight fragments: 2 col-tiles x 18 K-chunks ----
  s16x8 wf[2][18];
  float bias[2];
#pragma unroll
  for (int n = 0; n < 2; ++n) {
    const int c    = w * 32 + n * 16 + lrow;       // local gate-col 0..255
    const int grow = (c & 3) * HID + blk * UPB + (c >> 2);
#pragma unroll
    for (int kk = 0; kk < 16; ++kk) {
      const float* p = Whh + (size_t)grow * HID + kk * 32 + lk * 8;
      wf[n][kk] = pack8(*(const f32x4*)p, *(const f32x4*)(p + 4));
    }
#pragma unroll
    for (int kk = 0; kk < 2; ++kk) {
      const float* p = Wih + (size_t)grow * IND + kk * 32 + lk * 8;
      wf[n][16 + kk] = pack8(*(const f32x4*)p, *(const f32x4*)(p + 4));
    }
    bias[n] = bih[grow] + bhh[grow];
  }

  if (tid == 0) go_flag = -1;
  __syncthreads();

  const bool is_gg = ((lrow & 3) == 2);           // tanh gate column
  const bool arow  = (lrow < BATCH_PG);           // lanes holding real A rows
  const bool prod  = (lk == 0) && ((lane & 3) == 0);
  float cst[2][4] = {{0.f, 0.f, 0.f, 0.f}, {0.f, 0.f, 0.f, 0.f}};
  float hn[2][4];

  // persistent A fragments: inactive lanes stay zero forever (masked loads)
  s16x8 ah[4] = {};
  s16x8 ax0 = {}, ax1 = {};

  const int xb = g * BATCH_PG + (lrow & 3);
  const float* xrow = x + (size_t)xb * (T_STEPS * IND) + lk * 8;

  // precomputed scatter constants (DPP-paired dword writes)
  const bool evn = (tid & 1) == 0;
  const int  ue  = tid & ~1;
  const int  sc_base = ((ue >> 3) << 4) + (ue & 7) * 2;   // slot*16 + byte
  const int  addr01 = (evn ? 0 : 1024) + (sc_base ^ (evn ? 0 : (4 << 4)));
  const int  addr23 = (evn ? 2048 : 3072) + (sc_base ^ (evn ? (8 << 4) : (12 << 4)));

  for (int t = 0; t < T_STEPS; ++t) {
    const int rb = t & 1;
    const unsigned tg = (unsigned)t;

    // x_t fragments (masked global loads; overlap the wait)
    if (arow) {
      const float* p = xrow + (size_t)t * IND;
      ax0 = pack8(*(const f32x4*)p,        *(const f32x4*)(p + 4));
      ax1 = pack8(*(const f32x4*)(p + 32), *(const f32x4*)(p + 36));
    }

    // ---- arrival: wave0 polls 64 sentinels, publishes to LDS ----
    if (w == 0) {
      const u64_t* sp = sent + ((size_t)(rb * NGROUPS + g) << 6) + lane;
      u64_t s = ALOAD64(sp);
      while (!__all((unsigned)s == tg)) s = ALOAD64(sp);
      if (lane == 0) go_flag = t;
    }
    __asm__ volatile("" ::: "memory");
    while (*(volatile int*)&go_flag < t) {}
    __asm__ volatile("" ::: "memory");

    // ---- data: load own 2 granules, verify tags (fallback re-poll) ----
    const u64_t* gp = hx + ((size_t)(rb * NGROUPS + g) << 10);
    u64_t v0 = ALOAD64(gp + 2 * tid), v1 = ALOAD64(gp + 2 * tid + 1);
    if (__builtin_expect((unsigned)v0 != tg || (unsigned)v1 != tg, 0)) {
      while ((unsigned)v0 != tg) v0 = ALOAD64(gp + 2 * tid);
      while ((unsigned)v1 != tg) v1 = ALOAD64(gp + 2 * tid + 1);
    }
    const unsigned hp0 = (unsigned)(v0 >> 32), hp1 = (unsigned)(v1 >> 32);

    // scatter: pair halves with quad neighbor -> 2 full-dword LDS writes
    {
      char* hb = (char*)hsm[rb];
      const unsigned q0 = qswap(hp0), q1 = qswap(hp1);
      const unsigned v01 = evn ? ((hp0 & 0xffffu) | (q0 << 16))
                               : ((q0 >> 16) | (hp0 & 0xffff0000u));
      const unsigned v23 = evn ? ((hp1 & 0xffffu) | (q1 << 16))
                               : ((q1 >> 16) | (hp1 & 0xffff0000u));
      *(unsigned*)(hb + addr01) = v01;
      *(unsigned*)(hb + addr23) = v23;
    }

    // x MFMAs seed 4 independent chains while the tile settles
    f32x4 acc00 = {0.f, 0.f, 0.f, 0.f}, acc01 = {0.f, 0.f, 0.f, 0.f};
    f32x4 acc10 = {0.f, 0.f, 0.f, 0.f}, acc11 = {0.f, 0.f, 0.f, 0.f};
    acc00 = __builtin_amdgcn_mfma_f32_16x16x32_bf16(ax0, wf[0][16], acc00, 0, 0, 0);
    acc01 = __builtin_amdgcn_mfma_f32_16x16x32_bf16(ax1, wf[0][17], acc01, 0, 0, 0);
    acc10 = __builtin_amdgcn_mfma_f32_16x16x32_bf16(ax0, wf[1][16], acc10, 0, 0, 0);
    acc11 = __builtin_amdgcn_mfma_f32_16x16x32_bf16(ax1, wf[1][17], acc11, 0, 0, 0);

    __syncthreads();

    // h MFMAs: masked reads (16 active lanes); kk 0..7 -> chain a, 8..15 -> b
    const char* rowp = (const char*)hsm[rb] + lrow * 1024;
    const int rxor = lrow << 2;   // slot ^= (row*4); slot granule = 16B
#pragma unroll
    for (int kk4 = 0; kk4 < 4; ++kk4) {
      if (arow) {
#pragma unroll
        for (int j = 0; j < 4; ++j)
          ah[j] = *(const s16x8*)(rowp + (((16 * kk4 + 4 * j + lk) ^ rxor) << 4));
      }
#pragma unroll
      for (int j = 0; j < 4; ++j) {
        const int kk = kk4 * 4 + j;
        if (kk4 < 2) {
          acc00 = __builtin_amdgcn_mfma_f32_16x16x32_bf16(ah[j], wf[0][kk], acc00, 0, 0, 0);
          acc10 = __builtin_amdgcn_mfma_f32_16x16x32_bf16(ah[j], wf[1][kk], acc10, 0, 0, 0);
        } else {
          acc01 = __builtin_amdgcn_mfma_f32_16x16x32_bf16(ah[j], wf[0][kk], acc01, 0, 0, 0);
          acc11 = __builtin_amdgcn_mfma_f32_16x16x32_bf16(ah[j], wf[1][kk], acc11, 0, 0, 0);
        }
      }
    }

    // gates: branchless nonlinearity + DPP quad broadcasts
#pragma unroll
    for (int n = 0; n < 2; ++n) {
      const f32x4 aA = n ? acc10 : acc00;
      const f32x4 aB = n ? acc11 : acc01;
#pragma unroll
      for (int r = 0; r < 4; ++r) {
        const float v  = (aA[r] + aB[r]) + bias[n];
        const float a  = is_gg ? (2.f * v) : (-v);
        const float e  = __expf(a);
        const float r1 = __builtin_amdgcn_rcpf(1.f + e);
        const float sg = is_gg ? (1.f - 2.f * r1) : r1;   // tanh or sigmoid
        const float vi = qbc<0x00>(sg);
        const float vf = qbc<0x55>(sg);
        const float vg = qbc<0xAA>(sg);
        const float vo = qbc<0xFF>(sg);
        const float c  = fmaf(vf, cst[n][r], vi * vg);
        cst[n][r] = c;
        const float th = 1.f - 2.f * __builtin_amdgcn_rcpf(1.f + __expf(2.f * c));
        hn[n][r] = vo * th;
      }
    }

    // producer lanes store tagged granules, then per-wave sentinel
    u64_t* op = hx + ((size_t)((rb ^ 1) * NGROUPS + g) << 10);
    const u64_t ntg = (u64_t)(unsigned)(t + 1);
    if (prod) {
#pragma unroll
      for (int n = 0; n < 2; ++n) {
        const int ul = w * 8 + n * 4 + (lrow >> 2);     // local unit 0..63
        const int gu = blk * UPB + ul;                  // global unit 0..511
        const unsigned p01 = (unsigned)f2bf(hn[n][0]) | ((unsigned)f2bf(hn[n][1]) << 16);
        const unsigned p23 = (unsigned)f2bf(hn[n][2]) | ((unsigned)f2bf(hn[n][3]) << 16);
        ASTORE64(op + 2 * gu,     ntg | ((u64_t)p01 << 32));
        ASTORE64(op + 2 * gu + 1, ntg | ((u64_t)p23 << 32));
        if (t == T_STEPS - 1) {
#pragma unroll
          for (int r = 0; r < 4; ++r) clsh[r][ul] = hn[n][r];
        }
      }
    }
    __asm__ volatile("s_waitcnt vmcnt(0)" ::: "memory");  // wave's sc1 stores at MALL
    if (lane == 0)
      ASTORE64(sent + ((size_t)((rb ^ 1) * NGROUPS + g) << 6) + blk * 8 + w,
               ntg | (ntg << 32));
  }

  // ---- classifier: per-block partials over its 64 units ----
  __syncthreads();
  if (w == 0) {
#pragma unroll
    for (int b = 0; b < BATCH_PG; ++b) {
      const float hv = clsh[b][lane];
      for (int cls = 0; cls < 10; ++cls) {
        float v = hv * Wcls[(size_t)cls * HID + blk * UPB + lane];
#pragma unroll
        for (int m = 32; m >= 1; m >>= 1) v += __shfl_xor(v, m);
        if (lane == 0) {
          if (blk == 0) v += bcls[cls];
          atomicAdd(&out[(g * BATCH_PG + b) * 10 + cls], v);
        }
      }
    }
  }
}

extern "C" void kernel_launch(void* const* d_in, const int* in_sizes, int n_in,
                              void* d_out, int out_size, void* d_ws, size_t ws_size,
                              hipStream_t stream) {
  const float* x    = (const float*)d_in[0];
  const float* Wih  = (const float*)d_in[1];
  const float* Whh  = (const float*)d_in[2];
  const float* bih  = (const float*)d_in[3];
  const float* bhh  = (const float*)d_in[4];
  const float* Wcls = (const float*)d_in[5];
  const float* bcls = (const float*)d_in[6];
  float* out = (float*)d_out;

  u64_t* hx   = (u64_t*)d_ws;                            // [2][32][1024] = 512 KiB
  u64_t* sent = (u64_t*)((uint8_t*)d_ws + 512 * 1024);   // [2][32][64]   = 32 KiB

  // replay-safe re-init: zero tags/sentinels (tag0 == step-0 data h=0) + out
  hipMemsetAsync(hx, 0, 2 * NGROUPS * 1024 * sizeof(u64_t), stream);
  hipMemsetAsync(sent, 0, 2 * NGROUPS * 64 * sizeof(u64_t), stream);
  hipMemsetAsync(out, 0, (size_t)out_size * sizeof(float), stream);

  void* args[] = {&x, &Wih, &Whh, &bih, &bhh, &Wcls, &bcls, &out, &hx, &sent};
  hipError_t e = hipLaunchCooperativeKernel(
      reinterpret_cast<const void*>(&lstm_persist), dim3(NGROUPS * BPG),
      dim3(NTHREADS), args, 0, stream);
  if (e != hipSuccess) {
    lstm_persist<<<dim3(NGROUPS * BPG), dim3(NTHREADS), 0, stream>>>(
        x, Wih, Whh, bih, bhh, Wcls, bcls, out, hx, sent);
  }
}